// Round 1
// baseline (312.291 us; speedup 1.0000x reference)
//
#include <hip/hip_runtime.h>
#include <cstdint>
#include <cstddef>

#define NB 16
#define SIDE 160
#define MM (SIDE*SIDE)      // 25600 anchors
#define NC 80
#define NG 32
#define TOPK 10
#define REGW 3.0f
#define INVC 1e9f

using ull = unsigned long long;

__device__ __forceinline__ unsigned f2sort(float f) {
    unsigned b = __float_as_uint(f);
    return b ^ ((unsigned)((int)b >> 31) | 0x80000000u);
}
__device__ __forceinline__ float sort2f(unsigned s) {
    unsigned b = s ^ ((s & 0x80000000u) ? 0x80000000u : 0xFFFFFFFFu);
    return __uint_as_float(b);
}

// ---------------- valid anchors: inside ANY gt of the image -----------------
__global__ __launch_bounds__(256) void k_valid(const float* __restrict__ anchors,
                                               const float* __restrict__ gt_boxes,
                                               unsigned char* __restrict__ valid) {
    int i = blockIdx.x * 256 + threadIdx.x;          // i in [0, NB*MM)
    int b = i / MM, m = i % MM;
    float ax = anchors[2*m], ay = anchors[2*m+1];
    const float* gb = gt_boxes + b*NG*4;
    unsigned char v = 0;
    for (int g = 0; g < NG; ++g) {
        float x1 = gb[4*g], y1 = gb[4*g+1], x2 = gb[4*g+2], y2 = gb[4*g+3];
        float d = fminf(fminf(ax-x1, ay-y1), fminf(x2-ax, y2-ay));
        v |= (d > 0.f) ? 1 : 0;
    }
    valid[i] = v;
}

// ---------------- per-(b,g) SimOTA candidate selection ----------------------
__global__ __launch_bounds__(256) void k_ota(
    const float* __restrict__ pred_cls, const float* __restrict__ pred_box,
    const float* __restrict__ gt_boxes, const int* __restrict__ gt_labels,
    const unsigned char* __restrict__ valid,
    int* __restrict__ cand_idx, float* __restrict__ cand_cost,
    int* __restrict__ dyn_k)
{
    __shared__ ull s_list[256*TOPK];   // 20 KiB
    __shared__ ull s_red[256];         //  2 KiB
    int bg  = blockIdx.x;
    int b   = bg >> 5;
    int tid = threadIdx.x;
    float gx1 = gt_boxes[bg*4+0], gy1 = gt_boxes[bg*4+1];
    float gx2 = gt_boxes[bg*4+2], gy2 = gt_boxes[bg*4+3];
    int   lab = gt_labels[bg];
    float garea = (gx2-gx1)*(gy2-gy1);

    ull lc[TOPK], li[TOPK];
    #pragma unroll
    for (int j = 0; j < TOPK; ++j) { lc[j] = ~0ull; li[j] = ~0ull; }

    const float* pb_base = pred_box + (size_t)b*MM*4;
    const float* pc_base = pred_cls + (size_t)b*MM*NC;
    const unsigned char* vb = valid + b*MM;

    for (int m = tid; m < MM; m += 256) {
        float4 pb = *(const float4*)(pb_base + 4*m);
        float iw = fmaxf(fminf(gx2, pb.z) - fmaxf(gx1, pb.x), 0.f);
        float ih = fmaxf(fminf(gy2, pb.w) - fmaxf(gy1, pb.y), 0.f);
        float inter = iw*ih;
        float pa  = (pb.z-pb.x)*(pb.w-pb.y);
        float uni = garea + pa - inter;
        float iou = inter / fmaxf(uni, 1e-8f);
        float l = pc_base[(size_t)m*NC + lab];
        float e  = expf(-fabsf(l));
        float rc = 1.f/(1.f+e);
        float sg = (l >= 0.f) ? rc : e*rc;            // sigmoid(l)
        float sp_pos = fmaxf(l, 0.f) + log1pf(e);     // softplus(l)
        float sp_neg = sp_pos - l;                    // softplus(-l)
        float bce = iou*sp_neg + (1.f-iou)*sp_pos;
        float d = iou - sg;
        float cost = bce*d*d + REGW*(-logf(iou + 1e-8f));
        if (!vb[m]) cost = INVC;

        ull ck = ((ull)f2sort(cost) << 32) | (unsigned)m;
        if (ck < lc[TOPK-1]) {
            ull cur = ck;
            #pragma unroll
            for (int j = 0; j < TOPK; ++j) {
                ull mn = lc[j] < cur ? lc[j] : cur;
                ull mx = lc[j] < cur ? cur   : lc[j];
                lc[j] = mn; cur = mx;
            }
        }
        ull ik = ((ull)(~f2sort(iou)) << 32) | (unsigned)m;
        if (ik < li[TOPK-1]) {
            ull cur = ik;
            #pragma unroll
            for (int j = 0; j < TOPK; ++j) {
                ull mn = li[j] < cur ? li[j] : cur;
                ull mx = li[j] < cur ? cur   : li[j];
                li[j] = mn; cur = mx;
            }
        }
    }

    // ---- merge: 10 globally smallest costs (ties -> lower anchor idx) ----
    #pragma unroll
    for (int j = 0; j < TOPK; ++j) s_list[tid*TOPK+j] = lc[j];
    __syncthreads();
    int p = 0;
    for (int r = 0; r < TOPK; ++r) {
        s_red[tid] = s_list[tid*TOPK + p];
        __syncthreads();
        for (int off = 128; off; off >>= 1) {
            if (tid < off) { ull o = s_red[tid+off]; if (o < s_red[tid]) s_red[tid] = o; }
            __syncthreads();
        }
        ull w = s_red[0];
        __syncthreads();
        if (s_list[tid*TOPK + p] == w) ++p;
        if (tid == 0) {
            cand_cost[bg*TOPK + r] = sort2f((unsigned)(w >> 32));
            cand_idx [bg*TOPK + r] = (int)(w & 0xFFFFFFFFull);
        }
    }
    __syncthreads();

    // ---- merge: 10 globally largest ious -> dyn_k ----
    #pragma unroll
    for (int j = 0; j < TOPK; ++j) s_list[tid*TOPK+j] = li[j];
    __syncthreads();
    p = 0;
    float isum = 0.f;
    for (int r = 0; r < TOPK; ++r) {
        s_red[tid] = s_list[tid*TOPK + p];
        __syncthreads();
        for (int off = 128; off; off >>= 1) {
            if (tid < off) { ull o = s_red[tid+off]; if (o < s_red[tid]) s_red[tid] = o; }
            __syncthreads();
        }
        ull w = s_red[0];
        __syncthreads();
        if (s_list[tid*TOPK + p] == w) ++p;
        if (tid == 0) isum += sort2f(~(unsigned)(w >> 32));
    }
    if (tid == 0) {
        int k = (int)isum;            // truncation toward zero, isum >= 0
        dyn_k[bg] = k < 1 ? 1 : k;
    }
}

// ---------------- scatter matches with conflict resolution ------------------
__global__ void k_match(const int* __restrict__ cand_idx,
                        const float* __restrict__ cand_cost,
                        const int* __restrict__ dyn_k,
                        ull* __restrict__ best) {
    int i = blockIdx.x*blockDim.x + threadIdx.x;
    if (i >= NB*NG*TOPK) return;
    int bg = i / TOPK, r = i - bg*TOPK;
    if (r >= dyn_k[bg]) return;
    int b = bg >> 5, g = bg & (NG-1);
    int m = cand_idx[i];
    ull key = ((ull)f2sort(cand_cost[i]) << 32) | (unsigned)g;
    atomicMin(&best[(size_t)b*MM + m], key);
}

// ---------------- per-anchor labels + GIoU loss -----------------------------
__global__ __launch_bounds__(256) void k_giou(
    const float* __restrict__ pred_box, const float* __restrict__ gt_boxes,
    const int* __restrict__ gt_labels, const ull* __restrict__ best,
    unsigned char* __restrict__ labels, float* __restrict__ accum) {
    int i = blockIdx.x*256 + threadIdx.x;      // exact grid: i < NB*MM
    int b = i / MM;
    float contrib = 0.f, cnt = 0.f;
    unsigned char lab = NC;
    ull key = best[i];
    if (key != ~0ull) {
        int g  = (int)(key & 0xFFFFFFFFull);
        int bg = b*NG + g;
        lab = (unsigned char)gt_labels[bg];
        float4 pb = *(const float4*)(pred_box + (size_t)i*4);
        float gx1 = gt_boxes[bg*4],   gy1 = gt_boxes[bg*4+1];
        float gx2 = gt_boxes[bg*4+2], gy2 = gt_boxes[bg*4+3];
        float iw = fmaxf(fminf(pb.z,gx2) - fmaxf(pb.x,gx1), 0.f);
        float ih = fmaxf(fminf(pb.w,gy2) - fmaxf(pb.y,gy1), 0.f);
        float inter = iw*ih;
        float a1 = fmaxf(pb.z-pb.x,0.f)*fmaxf(pb.w-pb.y,0.f);
        float a2 = fmaxf(gx2-gx1,0.f)*fmaxf(gy2-gy1,0.f);
        float uni = a1 + a2 - inter;
        float iou = inter / fmaxf(uni, 1e-7f);
        float cw = fmaxf(fmaxf(pb.z,gx2) - fminf(pb.x,gx1), 0.f);
        float ch = fmaxf(fmaxf(pb.w,gy2) - fminf(pb.y,gy1), 0.f);
        float ca = fmaxf(cw*ch, 1e-7f);
        float giou = iou - (ca - uni)/ca;
        contrib = 1.f - giou;
        cnt = 1.f;
    }
    labels[i] = lab;
    // block reduce
    for (int o = 32; o; o >>= 1) {
        contrib += __shfl_down(contrib, o);
        cnt     += __shfl_down(cnt, o);
    }
    __shared__ float sc[4], sn[4];
    int ln = threadIdx.x & 63, wv = threadIdx.x >> 6;
    if (ln == 0) { sc[wv] = contrib; sn[wv] = cnt; }
    __syncthreads();
    if (threadIdx.x == 0) {
        float c = sc[0]+sc[1]+sc[2]+sc[3];
        float n = sn[0]+sn[1]+sn[2]+sn[3];
        if (n != 0.f || c != 0.f) {
            atomicAdd(&accum[1], c);
            atomicAdd(&accum[2], n);
        }
    }
}

// ---------------- focal loss over all anchors x classes ---------------------
__global__ __launch_bounds__(256) void k_focal(
    const float* __restrict__ pred_cls, const unsigned char* __restrict__ labels,
    const unsigned char* __restrict__ mask, float* __restrict__ accum) {
    const unsigned total4 = (unsigned)NB*MM*NC/4;   // 8,192,000 float4s
    unsigned stride = gridDim.x * blockDim.x;
    float acc = 0.f;
    for (unsigned i4 = blockIdx.x*blockDim.x + threadIdx.x; i4 < total4; i4 += stride) {
        float4 xv = ((const float4*)pred_cls)[i4];
        unsigned base = i4*4;
        unsigned row  = base / NC;
        unsigned c0   = base - row*NC;
        unsigned lab  = labels[row];
        bool excl = mask[row] != 0;
        float xs0 = xv.x, xs1 = xv.y, xs2 = xv.z, xs3 = xv.w;
        float fr = 0.f;
        #pragma unroll
        for (int j = 0; j < 4; ++j) {
            float x = (j==0) ? xs0 : (j==1) ? xs1 : (j==2) ? xs2 : xs3;
            float e  = expf(-fabsf(x));
            float rc = 1.f/(1.f+e);
            float p  = (x >= 0.f) ? rc : e*rc;        // sigmoid
            float sp = fmaxf(x, 0.f) + log1pf(e);     // softplus(x)
            float f;
            if (c0 + (unsigned)j == lab) { float om = 1.f-p; f = (sp - x)*om*om*0.25f; }
            else                         { f = sp*p*p*0.75f; }
            fr += f;
        }
        if (!excl) acc += fr;
    }
    for (int o = 32; o; o >>= 1) acc += __shfl_down(acc, o);
    __shared__ float sw[4];
    int ln = threadIdx.x & 63, wv = threadIdx.x >> 6;
    if (ln == 0) sw[wv] = acc;
    __syncthreads();
    if (threadIdx.x == 0) {
        float s = sw[0]+sw[1]+sw[2]+sw[3];
        atomicAdd(&accum[0], s);
    }
}

// ---------------- final normalize -------------------------------------------
__global__ void k_final(const float* __restrict__ accum, float* __restrict__ out) {
    if (threadIdx.x == 0) {
        float nf = fmaxf(accum[2], 1.f);
        out[0] = accum[0]/nf;
        out[1] = accum[1]/nf;
    }
}

extern "C" void kernel_launch(void* const* d_in, const int* in_sizes, int n_in,
                              void* d_out, int out_size, void* d_ws, size_t ws_size,
                              hipStream_t stream) {
    const float* pred_cls  = (const float*)d_in[0];
    const float* pred_box  = (const float*)d_in[1];
    const float* anchors   = (const float*)d_in[2];
    const float* gt_boxes  = (const float*)d_in[3];
    const int*   gt_labels = (const int*)d_in[4];
    const unsigned char* mask = (const unsigned char*)d_in[5];
    float* out = (float*)d_out;

    char* ws = (char*)d_ws;
    float* accum = (float*)ws;                                 // [0]=S_cls [1]=S_giou [2]=count
    int*   dynk  = (int*)(ws + 256);                           // 512 ints
    int*   cidx  = (int*)(ws + 256 + 2048);                    // 5120 ints
    float* ccost = (float*)(ws + 256 + 2048 + 20480);          // 5120 floats
    unsigned char* valid  = (unsigned char*)(ws + 43264);      // NB*MM bytes
    unsigned char* labels = valid + (size_t)NB*MM;             // NB*MM bytes
    ull* best = (ull*)(ws + 43264 + 2*(size_t)NB*MM);          // NB*MM ulls (8-aligned)

    size_t needed = 43264 + 2*(size_t)NB*MM + (size_t)NB*MM*8;
    if (ws_size < needed) return;   // visible failure rather than corruption

    hipMemsetAsync(accum, 0, 16, stream);
    hipMemsetAsync(best, 0xFF, (size_t)NB*MM*8, stream);

    k_valid<<<NB*MM/256, 256, 0, stream>>>(anchors, gt_boxes, valid);
    k_ota<<<NB*NG, 256, 0, stream>>>(pred_cls, pred_box, gt_boxes, gt_labels,
                                     valid, cidx, ccost, dynk);
    k_match<<<(NB*NG*TOPK + 255)/256, 256, 0, stream>>>(cidx, ccost, dynk, best);
    k_giou<<<NB*MM/256, 256, 0, stream>>>(pred_box, gt_boxes, gt_labels, best, labels, accum);
    k_focal<<<2048, 256, 0, stream>>>(pred_cls, labels, mask, accum);
    k_final<<<1, 64, 0, stream>>>(accum, out);
}